// Round 4
// baseline (373.628 us; speedup 1.0000x reference)
//
#include <hip/hip_runtime.h>
#include <math.h>

#define HH 1024
#define WW 1024
#define OUTW 58            // output columns per wave (64 lanes - 6 halo)
#define RPB 4              // output rows per block (vertical slide length)
#define OFF(i) ((i)*8 - (i)*((i)-1)/2)   // packed upper-tri row offset

// DPP move with old=0 (invalid source lanes contribute 0)
template<int CTRL>
__device__ __forceinline__ float dpp0(float x) {
    return __int_as_float(
        __builtin_amdgcn_update_dpp(0, __float_as_int(x), CTRL, 0xf, 0xf, false));
}
// whole-wave shift right by 1 lane (crosses 16-lane row boundaries)
__device__ __forceinline__ float wshr1(float x) { return dpp0<0x138>(x); }

// fp64 1/sqrt(s): f32 rsq seed + 2 fp64 Newton steps -> full fp64 accuracy,
// ~9 ops instead of compiler's ~25-instr sqrt+div chain (8x per pixel, serial)
__device__ __forceinline__ double drsqrt_fast(double s) {
    double r = (double)__builtin_amdgcn_rsqf((float)s);
    r = r * (1.5 - 0.5 * s * r * r);
    r = r * (1.5 - 0.5 * s * r * r);
    return r;
}

__global__ __launch_bounds__(64, 4) void ls_sep_kernel(
    const float* __restrict__ inp,    // [3,H,W]
    const float* __restrict__ dep,    // [1,H,W]
    const float* __restrict__ alb,    // [3,H,W]
    const float* __restrict__ nrm,    // [3,H,W]
    float* __restrict__ out)          // [3,H,W]
{
    const int L  = threadIdx.x;               // lane 0..63
    const int HW = HH * WW;
    // lane L sums column x; its horizontal window (x-6..x) is centered at x-3
    const int x  = OUTW * blockIdx.x - 3 + L;
    const int y0 = RPB * blockIdx.y;
    const int px = x - 3;                     // output pixel column for this lane

    const int xc    = min(max(x, 0), WW - 1);
    const float xok = (x >= 0 && x < WW) ? 1.f : 0.f;

    float C[60];                              // running column sums (7 rows in y)
    #pragma unroll
    for (int k = 0; k < 60; k++) C[k] = 0.f;

    auto acc_row = [&](int yy, float sgn) {
        const int yc = min(max(yy, 0), HH - 1);
        const float ok = (yy >= 0 && yy < HH) ? xok : 0.f;
        const int p = yc * WW + xc;
        float fv[8], yv[3];
        fv[0] = 1.f;
        fv[1] = dep[p];
        fv[2] = alb[p];
        fv[3] = alb[p + HW];
        fv[4] = alb[p + 2 * HW];
        fv[5] = nrm[p];
        fv[6] = nrm[p + HW];
        fv[7] = nrm[p + 2 * HW];
        yv[0] = inp[p];
        yv[1] = inp[p + HW];
        yv[2] = inp[p + 2 * HW];
        const float s = sgn * ok;
        float fs[8];
        #pragma unroll
        for (int i = 0; i < 8; i++) fs[i] = fv[i] * s;
        int k = 0;
        #pragma unroll
        for (int i = 0; i < 8; i++)
            #pragma unroll
            for (int j = i; j < 8; j++) { C[k] = fmaf(fs[i], fv[j], C[k]); k++; }
        #pragma unroll
        for (int i = 0; i < 8; i++)
            #pragma unroll
            for (int c = 0; c < 3; c++)
                C[36 + i * 3 + c] = fmaf(fs[i], yv[c], C[36 + i * 3 + c]);
    };

    // preload rows y0-4 .. y0+2 (loop body does add(y+3), sub(y-4))
    #pragma unroll 1
    for (int yy = y0 - 4; yy < y0 + 3; yy++) acc_row(yy, 1.f);

    const int idxm4 = ((L - 4) & 63) << 2;    // bpermute byte index for lane L-4
    const int pxc = min(max(px, 0), WW - 1);
    const bool do_store = (L >= 6) && (px < WW);

    #pragma unroll 1
    for (int y = y0; y < y0 + RPB; y++) {
        acc_row(y + 3, 1.f);
        acc_row(y - 4, -1.f);

        // exact horizontal 7-tap: S(L) = sum of C over lanes L-6..L
        float S[60];
        #pragma unroll
        for (int k = 0; k < 60; k++) {
            const float xv = C[k];
            const float w1 = wshr1(xv);       // C(L-1)
            const float t1 = xv + w1;         // L-1..L
            const float w2 = wshr1(w1);       // C(L-2)
            const float t3 = t1 + w2;         // L-2..L
            const float w3 = wshr1(w2);       // C(L-3)
            const float t2 = t3 + w3;         // L-3..L
            const float pm = __int_as_float(
                __builtin_amdgcn_ds_bpermute(idxm4, __float_as_int(t3))); // L-6..L-4
            S[k] = t2 + pm;
        }

        // center-pixel features (column px, row y)
        const int pc = y * WW + pxc;
        float cf[8];
        cf[0] = 1.f;
        cf[1] = dep[pc];
        cf[2] = alb[pc];
        cf[3] = alb[pc + HW];
        cf[4] = alb[pc + 2 * HW];
        cf[5] = nrm[pc];
        cf[6] = nrm[pc + HW];
        cf[7] = nrm[pc + 2 * HW];

        // fp64 Cholesky of AtA (+eps I), packed upper-tri
        double A[36];
        #pragma unroll
        for (int k = 0; k < 36; k++) A[k] = (double)S[k];
        #pragma unroll
        for (int i = 0; i < 8; i++) A[OFF(i)] += 1.0e-4;

        double invd[8];
        #pragma unroll
        for (int i = 0; i < 8; i++) {
            double s = A[OFF(i)];
            #pragma unroll
            for (int k2 = 0; k2 < i; k2++) {
                const double u = A[OFF(k2) + i - k2];
                s -= u * u;
            }
            const double id = drsqrt_fast(s);
            invd[i] = id;
            #pragma unroll
            for (int j = i + 1; j < 8; j++) {
                double s2 = A[OFF(i) + j - i];
                #pragma unroll
                for (int k2 = 0; k2 < i; k2++)
                    s2 -= A[OFF(k2) + i - k2] * A[OFF(k2) + j - k2];
                A[OFF(i) + j - i] = s2 * id;
            }
        }

        // solve A w = f_center (single RHS), then out_c = w . AtY_c
        double z[8];
        #pragma unroll
        for (int i = 0; i < 8; i++) {
            double s = (double)cf[i];
            #pragma unroll
            for (int k2 = 0; k2 < i; k2++)
                s -= A[OFF(k2) + i - k2] * z[k2];
            z[i] = s * invd[i];
        }
        double w[8];
        #pragma unroll
        for (int i = 7; i >= 0; i--) {
            double s = z[i];
            #pragma unroll
            for (int j = i + 1; j < 8; j++)
                s -= A[OFF(i) + j - i] * w[j];
            w[i] = s * invd[i];
        }

        if (do_store) {
            const int p = y * WW + px;
            #pragma unroll
            for (int c = 0; c < 3; c++) {
                double r = 0.0;
                #pragma unroll
                for (int i = 0; i < 8; i++)
                    r += w[i] * (double)S[36 + i * 3 + c];
                out[c * HW + p] = (float)r;
            }
        }
    }
}

extern "C" void kernel_launch(void* const* d_in, const int* in_sizes, int n_in,
                              void* d_out, int out_size, void* d_ws, size_t ws_size,
                              hipStream_t stream) {
    const float* inp = (const float*)d_in[0];
    const float* dep = (const float*)d_in[1];
    const float* alb = (const float*)d_in[2];
    const float* nrm = (const float*)d_in[3];
    float* out = (float*)d_out;
    dim3 grid((WW + OUTW - 1) / OUTW, HH / RPB);   // 18 x 256
    ls_sep_kernel<<<grid, dim3(64), 0, stream>>>(inp, dep, alb, nrm, out);
}

// Round 5
// 139.324 us; speedup vs baseline: 2.6817x; 2.6817x over previous
//
#include <hip/hip_runtime.h>
#include <math.h>

#define HH 1024
#define WW 1024
#define OUTW 58            // output columns per wave (64 lanes - 6 halo)
#define RPB 4              // output rows per block (vertical slide length)
#define OFF(i) ((i)*8 - (i)*((i)-1)/2)   // packed upper-tri row offset

// NOTE: register floor of this kernel is ~128 VGPRs (C[60]+S[60]+fp64 A[36]).
// __launch_bounds__(64,4) forces a 64-VGPR cap -> 1.2 GB scratch spill, 3x
// regression (round 4). Keep (64,2): VGPR=128 already admits 4 waves/SIMD.

// DPP move, bound_ctrl=1 (invalid lanes read 0; fusable into v_add_f32_dpp)
template<int CTRL>
__device__ __forceinline__ float dpp0(float x) {
    return __int_as_float(
        __builtin_amdgcn_update_dpp(0, __float_as_int(x), CTRL, 0xf, 0xf, true));
}
// whole-wave shift right by 1 lane (crosses 16-lane row boundaries)
__device__ __forceinline__ float wshr1(float x) { return dpp0<0x138>(x); }

// fp64 1/sqrt(s): f32 rsq seed + 2 fp64 Newton steps -> full fp64 accuracy,
// ~9 ops instead of the ~25-instr fp64 sqrt+div chain (8x per pixel, serial)
__device__ __forceinline__ double drsqrt_fast(double s) {
    double r = (double)__builtin_amdgcn_rsqf((float)s);
    r = r * (1.5 - 0.5 * s * r * r);
    r = r * (1.5 - 0.5 * s * r * r);
    return r;
}

__global__ __launch_bounds__(64, 2) void ls_sep_kernel(
    const float* __restrict__ inp,    // [3,H,W]
    const float* __restrict__ dep,    // [1,H,W]
    const float* __restrict__ alb,    // [3,H,W]
    const float* __restrict__ nrm,    // [3,H,W]
    float* __restrict__ out)          // [3,H,W]
{
    const int L  = threadIdx.x;               // lane 0..63
    const int HW = HH * WW;
    // lane L sums column x; its horizontal window (x-6..x) is centered at x-3
    const int x  = OUTW * blockIdx.x - 3 + L;
    const int y0 = RPB * blockIdx.y;
    const int px = x - 3;                     // output pixel column for this lane

    const int xc    = min(max(x, 0), WW - 1);
    const float xok = (x >= 0 && x < WW) ? 1.f : 0.f;

    float C[60];                              // running column sums (7 rows in y)
    #pragma unroll
    for (int k = 0; k < 60; k++) C[k] = 0.f;

    auto acc_row = [&](int yy, float sgn) {
        const int yc = min(max(yy, 0), HH - 1);
        const float ok = (yy >= 0 && yy < HH) ? xok : 0.f;
        const int p = yc * WW + xc;
        float fv[8], yv[3];
        fv[0] = 1.f;
        fv[1] = dep[p];
        fv[2] = alb[p];
        fv[3] = alb[p + HW];
        fv[4] = alb[p + 2 * HW];
        fv[5] = nrm[p];
        fv[6] = nrm[p + HW];
        fv[7] = nrm[p + 2 * HW];
        yv[0] = inp[p];
        yv[1] = inp[p + HW];
        yv[2] = inp[p + 2 * HW];
        const float s = sgn * ok;
        float fs[8];
        #pragma unroll
        for (int i = 0; i < 8; i++) fs[i] = fv[i] * s;
        int k = 0;
        #pragma unroll
        for (int i = 0; i < 8; i++)
            #pragma unroll
            for (int j = i; j < 8; j++) { C[k] = fmaf(fs[i], fv[j], C[k]); k++; }
        #pragma unroll
        for (int i = 0; i < 8; i++)
            #pragma unroll
            for (int c = 0; c < 3; c++)
                C[36 + i * 3 + c] = fmaf(fs[i], yv[c], C[36 + i * 3 + c]);
    };

    // preload rows y0-4 .. y0+2 (loop body does add(y+3), sub(y-4))
    #pragma unroll 1
    for (int yy = y0 - 4; yy < y0 + 3; yy++) acc_row(yy, 1.f);

    const int idxm4 = ((L - 4) & 63) << 2;    // bpermute byte index for lane L-4
    const int pxc = min(max(px, 0), WW - 1);
    const bool do_store = (L >= 6) && (px < WW);

    #pragma unroll 1
    for (int y = y0; y < y0 + RPB; y++) {
        acc_row(y + 3, 1.f);
        acc_row(y - 4, -1.f);

        // exact horizontal 7-tap: S(L) = sum of C over lanes L-6..L
        float S[60];
        #pragma unroll
        for (int k = 0; k < 60; k++) {
            const float xv = C[k];
            const float w1 = wshr1(xv);       // C(L-1)
            const float t1 = xv + w1;         // L-1..L
            const float w2 = wshr1(w1);       // C(L-2)
            const float t3 = t1 + w2;         // L-2..L
            const float w3 = wshr1(w2);       // C(L-3)
            const float t2 = t3 + w3;         // L-3..L
            const float pm = __int_as_float(
                __builtin_amdgcn_ds_bpermute(idxm4, __float_as_int(t3))); // L-6..L-4
            S[k] = t2 + pm;
        }

        // center-pixel features (column px, row y)
        const int pc = y * WW + pxc;
        float cf[8];
        cf[0] = 1.f;
        cf[1] = dep[pc];
        cf[2] = alb[pc];
        cf[3] = alb[pc + HW];
        cf[4] = alb[pc + 2 * HW];
        cf[5] = nrm[pc];
        cf[6] = nrm[pc + HW];
        cf[7] = nrm[pc + 2 * HW];

        // fp64 Cholesky of AtA (+eps I), packed upper-tri
        double A[36];
        #pragma unroll
        for (int k = 0; k < 36; k++) A[k] = (double)S[k];
        #pragma unroll
        for (int i = 0; i < 8; i++) A[OFF(i)] += 1.0e-4;

        double invd[8];
        #pragma unroll
        for (int i = 0; i < 8; i++) {
            double s = A[OFF(i)];
            #pragma unroll
            for (int k2 = 0; k2 < i; k2++) {
                const double u = A[OFF(k2) + i - k2];
                s -= u * u;
            }
            const double id = drsqrt_fast(s);
            invd[i] = id;
            #pragma unroll
            for (int j = i + 1; j < 8; j++) {
                double s2 = A[OFF(i) + j - i];
                #pragma unroll
                for (int k2 = 0; k2 < i; k2++)
                    s2 -= A[OFF(k2) + i - k2] * A[OFF(k2) + j - k2];
                A[OFF(i) + j - i] = s2 * id;
            }
        }

        // solve A w = f_center (single RHS), then out_c = w . AtY_c
        double z[8];
        #pragma unroll
        for (int i = 0; i < 8; i++) {
            double s = (double)cf[i];
            #pragma unroll
            for (int k2 = 0; k2 < i; k2++)
                s -= A[OFF(k2) + i - k2] * z[k2];
            z[i] = s * invd[i];
        }
        double w[8];
        #pragma unroll
        for (int i = 7; i >= 0; i--) {
            double s = z[i];
            #pragma unroll
            for (int j = i + 1; j < 8; j++)
                s -= A[OFF(i) + j - i] * w[j];
            w[i] = s * invd[i];
        }

        if (do_store) {
            const int p = y * WW + px;
            #pragma unroll
            for (int c = 0; c < 3; c++) {
                double r = 0.0;
                #pragma unroll
                for (int i = 0; i < 8; i++)
                    r += w[i] * (double)S[36 + i * 3 + c];
                out[c * HW + p] = (float)r;
            }
        }
    }
}

extern "C" void kernel_launch(void* const* d_in, const int* in_sizes, int n_in,
                              void* d_out, int out_size, void* d_ws, size_t ws_size,
                              hipStream_t stream) {
    const float* inp = (const float*)d_in[0];
    const float* dep = (const float*)d_in[1];
    const float* alb = (const float*)d_in[2];
    const float* nrm = (const float*)d_in[3];
    float* out = (float*)d_out;
    dim3 grid((WW + OUTW - 1) / OUTW, HH / RPB);   // 18 x 256
    ls_sep_kernel<<<grid, dim3(64), 0, stream>>>(inp, dep, alb, nrm, out);
}

// Round 6
// 128.773 us; speedup vs baseline: 2.9015x; 1.0819x over previous
//
#include <hip/hip_runtime.h>
#include <math.h>

#define HH 1024
#define WW 1024
#define OUTW 58            // output columns per wave (64 lanes - 6 halo)
#define RPB 4              // output rows per WAVE (vertical slide length)
#define WPB 4              // waves per block (independent y-strips, no barrier)
#define OFF(i) ((i)*8 - (i)*((i)-1)/2)   // packed upper-tri row offset

// NOTE round-4 lesson: register floor ~128 VGPRs; forcing a lower cap via
// launch_bounds causes a 1.2 GB scratch spill and 3x regression. Keep the
// (block,2) contract that empirically yields VGPR=128, no spill.

// DPP move, bound_ctrl=1 (invalid lanes read 0; fusable into v_add_f32_dpp)
template<int CTRL>
__device__ __forceinline__ float dpp0(float x) {
    return __int_as_float(
        __builtin_amdgcn_update_dpp(0, __float_as_int(x), CTRL, 0xf, 0xf, true));
}
// whole-wave shift right by 1 lane (crosses 16-lane row boundaries)
__device__ __forceinline__ float wshr1(float x) { return dpp0<0x138>(x); }

// fp32 1/sqrt: v_rsq_f32 seed + 1 Newton step -> ~1ulp fp32
__device__ __forceinline__ float frsqrt_fast(float s) {
    float r = __builtin_amdgcn_rsqf(s);
    r = r * (1.5f - 0.5f * s * r * r);
    return r;
}

__global__ __launch_bounds__(WPB * 64, 2) void ls_sep_kernel(
    const float* __restrict__ inp,    // [3,H,W]
    const float* __restrict__ dep,    // [1,H,W]
    const float* __restrict__ alb,    // [3,H,W]
    const float* __restrict__ nrm,    // [3,H,W]
    float* __restrict__ out)          // [3,H,W]
{
    const int L  = threadIdx.x & 63;          // lane 0..63
    const int wv = threadIdx.x >> 6;          // wave 0..3 (independent y-strip)
    const int HW = HH * WW;
    // lane L sums column x; its horizontal window (x-6..x) is centered at x-3
    const int x  = OUTW * blockIdx.x - 3 + L;
    const int y0 = (RPB * WPB) * blockIdx.y + RPB * wv;
    const int px = x - 3;                     // output pixel column for this lane

    const int xc    = min(max(x, 0), WW - 1);
    const float xok = (x >= 0 && x < WW) ? 1.f : 0.f;

    float C[60];                              // running column sums (7 rows in y)
    #pragma unroll
    for (int k = 0; k < 60; k++) C[k] = 0.f;

    auto acc_row = [&](int yy, float sgn) {
        const int yc = min(max(yy, 0), HH - 1);
        const float ok = (yy >= 0 && yy < HH) ? xok : 0.f;
        const int p = yc * WW + xc;
        float fv[8], yv[3];
        fv[0] = 1.f;
        fv[1] = dep[p];
        fv[2] = alb[p];
        fv[3] = alb[p + HW];
        fv[4] = alb[p + 2 * HW];
        fv[5] = nrm[p];
        fv[6] = nrm[p + HW];
        fv[7] = nrm[p + 2 * HW];
        yv[0] = inp[p];
        yv[1] = inp[p + HW];
        yv[2] = inp[p + 2 * HW];
        const float s = sgn * ok;
        float fs[8];
        #pragma unroll
        for (int i = 0; i < 8; i++) fs[i] = fv[i] * s;
        int k = 0;
        #pragma unroll
        for (int i = 0; i < 8; i++)
            #pragma unroll
            for (int j = i; j < 8; j++) { C[k] = fmaf(fs[i], fv[j], C[k]); k++; }
        #pragma unroll
        for (int i = 0; i < 8; i++)
            #pragma unroll
            for (int c = 0; c < 3; c++)
                C[36 + i * 3 + c] = fmaf(fs[i], yv[c], C[36 + i * 3 + c]);
    };

    // preload rows y0-4 .. y0+2 (loop body does add(y+3), sub(y-4))
    #pragma unroll 1
    for (int yy = y0 - 4; yy < y0 + 3; yy++) acc_row(yy, 1.f);

    const int idxm4 = ((L - 4) & 63) << 2;    // bpermute byte index for lane L-4
    const int pxc = min(max(px, 0), WW - 1);
    const bool do_store = (L >= 6) && (px < WW);

    #pragma unroll 1
    for (int y = y0; y < y0 + RPB; y++) {
        acc_row(y + 3, 1.f);
        acc_row(y - 4, -1.f);

        // exact horizontal 7-tap: S(L) = sum of C over lanes L-6..L
        float S[60];
        #pragma unroll
        for (int k = 0; k < 60; k++) {
            const float xv = C[k];
            const float w1 = wshr1(xv);       // C(L-1)
            const float t1 = xv + w1;         // L-1..L
            const float w2 = wshr1(w1);       // C(L-2)
            const float t3 = t1 + w2;         // L-2..L
            const float w3 = wshr1(w2);       // C(L-3)
            const float t2 = t3 + w3;         // L-3..L
            const float pm = __int_as_float(
                __builtin_amdgcn_ds_bpermute(idxm4, __float_as_int(t3))); // L-6..L-4
            S[k] = t2 + pm;
        }

        // center-pixel features (column px, row y)
        const int pc = y * WW + pxc;
        float cf[8];
        cf[0] = 1.f;
        cf[1] = dep[pc];
        cf[2] = alb[pc];
        cf[3] = alb[pc + HW];
        cf[4] = alb[pc + 2 * HW];
        cf[5] = nrm[pc];
        cf[6] = nrm[pc + HW];
        cf[7] = nrm[pc + 2 * HW];

        // fp32 Cholesky of AtA (+eps I), packed upper-tri.
        // Backward error ~8*ulp*||A|| ~ 3e-5: same order as the fp32 box-sum
        // perturbation -> absmax budget ~2e-2 vs threshold 5.9e-2.
        float A[36];
        #pragma unroll
        for (int k = 0; k < 36; k++) A[k] = S[k];
        #pragma unroll
        for (int i = 0; i < 8; i++) A[OFF(i)] += 1.0e-4f;

        float invd[8];
        #pragma unroll
        for (int i = 0; i < 8; i++) {
            float s = A[OFF(i)];
            #pragma unroll
            for (int k2 = 0; k2 < i; k2++) {
                const float u = A[OFF(k2) + i - k2];
                s = fmaf(-u, u, s);
            }
            const float id = frsqrt_fast(s);
            invd[i] = id;
            #pragma unroll
            for (int j = i + 1; j < 8; j++) {
                float s2 = A[OFF(i) + j - i];
                #pragma unroll
                for (int k2 = 0; k2 < i; k2++)
                    s2 = fmaf(-A[OFF(k2) + i - k2], A[OFF(k2) + j - k2], s2);
                A[OFF(i) + j - i] = s2 * id;
            }
        }

        // solve A w = f_center (single RHS), then out_c = w . AtY_c
        float z[8];
        #pragma unroll
        for (int i = 0; i < 8; i++) {
            float s = cf[i];
            #pragma unroll
            for (int k2 = 0; k2 < i; k2++)
                s = fmaf(-A[OFF(k2) + i - k2], z[k2], s);
            z[i] = s * invd[i];
        }
        float w[8];
        #pragma unroll
        for (int i = 7; i >= 0; i--) {
            float s = z[i];
            #pragma unroll
            for (int j = i + 1; j < 8; j++)
                s = fmaf(-A[OFF(i) + j - i], w[j], s);
            w[i] = s * invd[i];
        }

        if (do_store) {
            const int p = y * WW + px;
            #pragma unroll
            for (int c = 0; c < 3; c++) {
                float r = 0.f;
                #pragma unroll
                for (int i = 0; i < 8; i++)
                    r = fmaf(w[i], S[36 + i * 3 + c], r);
                out[c * HW + p] = r;
            }
        }
    }
}

extern "C" void kernel_launch(void* const* d_in, const int* in_sizes, int n_in,
                              void* d_out, int out_size, void* d_ws, size_t ws_size,
                              hipStream_t stream) {
    const float* inp = (const float*)d_in[0];
    const float* dep = (const float*)d_in[1];
    const float* alb = (const float*)d_in[2];
    const float* nrm = (const float*)d_in[3];
    float* out = (float*)d_out;
    dim3 grid((WW + OUTW - 1) / OUTW, HH / (RPB * WPB));   // 18 x 64, 256-thr blocks
    ls_sep_kernel<<<grid, dim3(WPB * 64), 0, stream>>>(inp, dep, alb, nrm, out);
}